// Round 9
// baseline (1398.234 us; speedup 1.0000x reference)
//
#include <hip/hip_runtime.h>
#include <hip/hip_bf16.h>

#define HH 512
#define FF 128
#define BB 2048
#define TT 96
#define NSTEP 96
#define NGATE 2048
#define NTOT 2176
#define GRP 16          // row groups (128 rows each) — XCD-local under id%8 dispatch
#define CPB 32          // col-part blocks per group

typedef short short8 __attribute__((ext_vector_type(8)));
typedef float f32x4 __attribute__((ext_vector_type(4)));

__device__ __forceinline__ float sigmoidf_(float x) { return 1.f / (1.f + __expf(-x)); }
__device__ __forceinline__ float tanhf_(float x) {
    float e = __expf(-2.f * fabsf(x));
    float t = (1.f - e) / (1.f + e);
    return x < 0.f ? -t : t;
}

// byte offset of element (m, k) in fragment order: 16(m) x 32(k) tiles of 1 KB,
// lane = (m&15) + 16*((k>>3)&3) holds bytes [lane*16, lane*16+16).
__device__ __forceinline__ size_t frag_off(int m, int k, int K) {
    return (size_t)((m >> 4) * (K >> 5) + (k >> 5)) * 1024
         + (size_t)(((k >> 3) & 3) * 256 + (m & 15) * 16 + (k & 7) * 2);
}

__device__ __forceinline__ short bf16bits(float f) {
    __hip_bfloat16 b = __float2bfloat16(f);
    return *(short*)&b;
}

// Gate-row layout (gates as the MFMA M dim): gate-row n (0..2047):
//   j = (n>>4)*4 + ((n>>2)&3), gate = n&3  (0=r, 1=z, 2=i_n(comb), 3=h_n)
// -> C fragment puts all 4 gates of one j into one lane's 4 acc registers
// (quad = j-within-tile, reg = gate). n>=2048: fc_w row -> Wfc.
// (verified correct in rounds 5/7)
__global__ __launch_bounds__(256) void build_weights(
    const float* __restrict__ w_ih, const float* __restrict__ w_hh,
    const float* __restrict__ b_ih, const float* __restrict__ b_hh,
    const float* __restrict__ fc_w, const float* __restrict__ fc_b,
    char* __restrict__ Wg, char* __restrict__ W0g, char* __restrict__ Wfc,
    float* __restrict__ bias, float* __restrict__ bias0)
{
    const int n = blockIdx.x;
    const int tid = threadIdx.x;
    __shared__ float wih_s[FF];
    const bool is_out = (n >= NGATE);
    int gate = 3, gidx = 0, f = 0;
    if (is_out) {
        f = n - NGATE;
    } else {
        int j = (n >> 4) * 4 + ((n >> 2) & 3);
        gate = n & 3;
        gidx = (gate == 0) ? j : (gate == 1) ? (512 + j) : (1024 + j);
    }
    if (!is_out && gate != 3 && tid < FF) wih_s[tid] = w_ih[gidx * FF + tid];
    __syncthreads();

    for (int k = tid; k < HH; k += 256) {
        float w, w0;
        if (is_out) {
            w = fc_w[f * HH + k];
            w0 = 0.f;
        } else if (gate == 3) {
            w = w_hh[gidx * HH + k];
            w0 = w;
        } else {
            float comb = 0.f;
#pragma unroll 8
            for (int ff2 = 0; ff2 < FF; ++ff2) comb += wih_s[ff2] * fc_w[ff2 * HH + k];
            if (gate == 2) { w = comb; w0 = 0.f; }
            else { float whh = w_hh[gidx * HH + k]; w = whh + comb; w0 = whh; }
        }
        if (is_out) {
            *(short*)(Wfc + frag_off(f, k, HH)) = bf16bits(w);
        } else {
            *(short*)(Wg  + frag_off(n, k, HH)) = bf16bits(w);
            *(short*)(W0g + frag_off(n, k, HH)) = bf16bits(w0);
        }
    }
    if (tid == 0 && !is_out) {
        float b, b0;
        float cb = 0.f;
        if (gate != 3)
            for (int ff2 = 0; ff2 < FF; ++ff2) cb += fc_b[ff2] * w_ih[gidx * FF + ff2];
        if (gate <= 1)      { float s2 = b_ih[gidx] + b_hh[gidx]; b = s2 + cb; b0 = s2; }
        else if (gate == 2) { b = b_ih[gidx] + cb; b0 = b_ih[gidx]; }
        else                { b = b_hh[gidx]; b0 = b_hh[gidx]; }
        bias[n] = b; bias0[n] = b0;
    }
}

// hidden (fp32 row-major) -> h_0 bf16 in fragment order; zero sync flags.
__global__ __launch_bounds__(256) void init_misc(
    const float* __restrict__ hidden, char* __restrict__ hfrag, int* __restrict__ cnt)
{
    int i = blockIdx.x * 256 + threadIdx.x;  // 131072 granules of 8 k-elements
    int row = i >> 6, k0 = (i & 63) << 3;
    short8 v;
#pragma unroll
    for (int t = 0; t < 8; ++t) v[t] = bf16bits(hidden[(size_t)row * HH + k0 + t]);
    *(short8*)(hfrag + frag_off(row, k0, HH)) = v;
    if (i < GRP * NSTEP * CPB) cnt[i] = 0;
}

// Persistent GRU, operand-swapped, register-resident weight halves.
// 512 blocks = 16 groups x 32 col-parts, 2 blocks/CU (LDS 68 KB). Map g=id&15:
// co-resident blocks (id, id+256) serve the SAME group -> shared Hb panel via L1
// (r7-proven; cross-group maps and phase seeding both failed, r2/r4/r8).
// MFMA: A = gate weights (M = gate-row), B = h (N = batch, global).
// LDS-redundancy fix: all 4 waves read identical weights from LDS (4x, the
// largest pipe at ~33% of the period). Each wave now holds M-tiles 0-1
// PERMANENTLY in registers (Wreg[2][16] = 128 VGPR, loaded once) and streams
// only tiles 2-3 from LDS -> ds_read_b128 per it: 4 -> 2, LDS pipe halved.
// Occupancy stays 2 blocks/CU: LDS-bound (68 KB), VGPR <=256 bucket keeps
// 2 waves/SIMD; launch_bounds(256,2) enforces the cap. Wreg K-loop indices are
// compile-time (full unroll). Depth-6 Hb window, lane-local shfl-free epilogue,
// fc deduped by step-phase (s&3 == c>>3) — all r7-proven.
__global__ __launch_bounds__(256, 2) void gru_persist(
    const char* __restrict__ Wg, const char* __restrict__ W0g, const char* __restrict__ Wfc,
    const float* __restrict__ bias, const float* __restrict__ bias0,
    const float* __restrict__ fc_b, const float* __restrict__ hidden,
    char* __restrict__ hfrag0, char* __restrict__ hfrag1,
    float* __restrict__ out, int* __restrict__ cnt)
{
    __shared__ __align__(16) short Bs[32768];   // 64 KB weights: [mt(4)][chunk(16)][lane*8]
    __shared__ __align__(16) short hfr[2048];   // 4 KB packed h_new [row(128)][col(16)]

    const int tid = threadIdx.x;
    const int lane = tid & 63, w = tid >> 6;
    const int l15 = lane & 15, quad = lane >> 4;
    const int g = blockIdx.x & 15, c = blockIdx.x >> 4;   // group on XCD (g&7)

    const char* aB0 = hfrag0 + (size_t)(g * 8 + w * 2) * 16384 + lane * 16;
    const char* aB1 = hfrag1 + (size_t)(g * 8 + w * 2) * 16384 + lane * 16;
    const char* bf  = Wfc + (size_t)(c & 7) * 16384 + lane * 16;
    const char* wlds = (const char*)Bs + lane * 16;
    const int fcq = c >> 3;                    // this block's fc step-phase

    f32x4 bv4[4];
#pragma unroll
    for (int mt = 0; mt < 4; ++mt)
        bv4[mt] = *(const f32x4*)&bias[c * 64 + mt * 16 + quad * 4];
    const f32x4 fcb4 = *(const f32x4*)&fc_b[(c & 7) * 16 + quad * 4];

    // fp32 carry h: carry[mt][btl] for (batch = g*128 + w*32 + btl*16 + l15,
    //                                   hcol = c*16 + mt*4 + quad)
    float carry[4][2];
#pragma unroll
    for (int mt = 0; mt < 4; ++mt)
#pragma unroll
        for (int btl = 0; btl < 2; ++btl)
            carry[mt][btl] =
                hidden[(size_t)(g * 128 + w * 32 + btl * 16 + l15) * HH
                       + c * 16 + mt * 4 + quad];

    int* const fl = cnt + g * (NSTEP * CPB);   // flags for this group: [s][c]

    // ---- stage this block's 64 gate rows of Wg into LDS (once) ----
    {
        const char* wsrc = Wg + (size_t)c * 65536;
#pragma unroll
        for (int i = 0; i < 16; ++i) {
            int idx = i * 256 + tid;
            *(int4*)((char*)Bs + idx * 16) = *(const int4*)(wsrc + (size_t)idx * 16);
        }
    }
    __syncthreads();

    // ---- M-tiles 0,1 -> registers, once (128 VGPR; tiles 2,3 stay in LDS) ----
    short8 Wreg[2][16];
#pragma unroll
    for (int mt = 0; mt < 2; ++mt)
#pragma unroll
        for (int p = 0; p < 16; ++p)
            Wreg[mt][p] = *(const short8*)(wlds + (size_t)(mt * 16 + p) * 1024);

    // wait for the group's step-s broadcast (32 flags), then invalidate vector L1.
    auto grp_wait = [&](int s) {
        if (w == 0) {
            if (lane < 32) {
                const int* fp = fl + s * CPB + lane;
                while (__hip_atomic_load(fp, __ATOMIC_RELAXED, __HIP_MEMORY_SCOPE_AGENT) == 0)
                    __builtin_amdgcn_s_sleep(1);
            }
            asm volatile("buffer_inv sc0\n\ts_waitcnt vmcnt(0)" ::: "memory");
        }
        __syncthreads();
        asm volatile("" ::: "memory");
    };

    // lane-local full-wave gates -> carry -> hfr pack -> frag store -> signal
    auto epilogue = [&](f32x4 (&acc)[4][2], int s, char* hout) {
#pragma unroll
        for (int mt = 0; mt < 4; ++mt)
#pragma unroll
            for (int btl = 0; btl < 2; ++btl) {
                f32x4 a = acc[mt][btl];
                float r  = sigmoidf_(a[0]);
                float z  = sigmoidf_(a[1]);
                float nv = tanhf_(a[2] + r * a[3]);
                float hn = (1.f - z) * nv + z * carry[mt][btl];
                carry[mt][btl] = hn;
                hfr[(w * 32 + btl * 16 + l15) * 16 + mt * 4 + quad] = bf16bits(hn);
            }
        __syncthreads();
        {
            int lrow = tid >> 1, half = tid & 1;
            size_t off = (size_t)((g * 8 + (lrow >> 4)) * 16 + (c >> 1)) * 1024
                       + (size_t)((((c << 1) + half) & 3) * 256 + (lrow & 15) * 16);
            *(int4*)(hout + off) = *(const int4*)&hfr[lrow * 16 + half * 8];
        }
        asm volatile("s_waitcnt vmcnt(0)" ::: "memory");
        __syncthreads();
        if (tid == 0)
            __hip_atomic_store(fl + s * CPB + c, 1, __ATOMIC_RELAXED, __HIP_MEMORY_SCOPE_AGENT);
    };

    // ---- step 0: x=0 weights streamed from global (one step, amortized) ----
    {
        f32x4 acc[4][2];
#pragma unroll
        for (int mt = 0; mt < 4; ++mt) {
            f32x4 b0 = *(const f32x4*)&bias0[c * 64 + mt * 16 + quad * 4];
            acc[mt][0] = b0; acc[mt][1] = b0;
        }
        const char* w0b = W0g + (size_t)c * 65536 + lane * 16;
        short8 W0[2][4]; short8 Hb[2][2];
#pragma unroll
        for (int p = 0; p < 2; ++p) {
#pragma unroll
            for (int mt = 0; mt < 4; ++mt)
                W0[p][mt] = *(const short8*)(w0b + (size_t)(mt * 16 + p) * 1024);
#pragma unroll
            for (int btl = 0; btl < 2; ++btl)
                Hb[p][btl] = *(const short8*)(aB0 + btl * 16384 + p * 1024);
        }
#pragma unroll
        for (int it = 0; it < 16; ++it) {
            const int sl = it & 1;
#pragma unroll
            for (int mt = 0; mt < 4; ++mt)
#pragma unroll
                for (int btl = 0; btl < 2; ++btl)
                    acc[mt][btl] = __builtin_amdgcn_mfma_f32_16x16x32_bf16(W0[sl][mt], Hb[sl][btl], acc[mt][btl], 0, 0, 0);
            if (it + 2 < 16) {
#pragma unroll
                for (int mt = 0; mt < 4; ++mt)
                    W0[sl][mt] = *(const short8*)(w0b + (size_t)(mt * 16 + it + 2) * 1024);
#pragma unroll
                for (int btl = 0; btl < 2; ++btl)
                    Hb[sl][btl] = *(const short8*)(aB0 + btl * 16384 + (it + 2) * 1024);
            }
        }
        epilogue(acc, 0, hfrag1);
    }

    // ---- steps 1..95: mt 0,1 from Wreg, mt 2,3 from LDS, Hb depth-6, fc /4 ----
    for (int s = 1; s < 96; ++s) {
        const char* ab = (s & 1) ? aB1 : aB0;
        char* hout = (s & 1) ? hfrag0 : hfrag1;
        const bool dofc = ((s & 3) == fcq);

        f32x4 acc[4][2];
#pragma unroll
        for (int mt = 0; mt < 4; ++mt) {
            acc[mt][0] = bv4[mt]; acc[mt][1] = bv4[mt];
        }
        f32x4 fca[2] = {{0.f,0.f,0.f,0.f},{0.f,0.f,0.f,0.f}};

        // barrier-independent preloads: LDS weight frags mt 2,3 (+ fc frags)
        short8 Wa[2][2]; short8 Wf[2];
#pragma unroll
        for (int p = 0; p < 2; ++p)
#pragma unroll
            for (int m2 = 0; m2 < 2; ++m2)
                Wa[p][m2] = *(const short8*)(wlds + (size_t)((2 + m2) * 16 + p) * 1024);
        if (dofc) {
            Wf[0] = *(const short8*)(bf);
            Wf[1] = *(const short8*)(bf + 1024);
        }

        grp_wait(s - 1);

        short8 Hb[6][2];
#pragma unroll
        for (int p = 0; p < 6; ++p)
#pragma unroll
            for (int btl = 0; btl < 2; ++btl)
                Hb[p][btl] = *(const short8*)(ab + btl * 16384 + p * 1024);

#pragma unroll
        for (int it = 0; it < 16; ++it) {
            const int sa = it % 6, sw = it & 1;
#pragma unroll
            for (int btl = 0; btl < 2; ++btl) {
                acc[0][btl] = __builtin_amdgcn_mfma_f32_16x16x32_bf16(Wreg[0][it], Hb[sa][btl], acc[0][btl], 0, 0, 0);
                acc[1][btl] = __builtin_amdgcn_mfma_f32_16x16x32_bf16(Wreg[1][it], Hb[sa][btl], acc[1][btl], 0, 0, 0);
                acc[2][btl] = __builtin_amdgcn_mfma_f32_16x16x32_bf16(Wa[sw][0],  Hb[sa][btl], acc[2][btl], 0, 0, 0);
                acc[3][btl] = __builtin_amdgcn_mfma_f32_16x16x32_bf16(Wa[sw][1],  Hb[sa][btl], acc[3][btl], 0, 0, 0);
            }
            if (dofc) {
                fca[0] = __builtin_amdgcn_mfma_f32_16x16x32_bf16(Wf[sw], Hb[sa][0], fca[0], 0, 0, 0);
                fca[1] = __builtin_amdgcn_mfma_f32_16x16x32_bf16(Wf[sw], Hb[sa][1], fca[1], 0, 0, 0);
            }
            if (it + 6 < 16) {
#pragma unroll
                for (int btl = 0; btl < 2; ++btl)
                    Hb[sa][btl] = *(const short8*)(ab + btl * 16384 + (it + 6) * 1024);
            }
            if (it + 2 < 16) {
#pragma unroll
                for (int m2 = 0; m2 < 2; ++m2)
                    Wa[sw][m2] = *(const short8*)(wlds + (size_t)((2 + m2) * 16 + it + 2) * 1024);
                if (dofc) Wf[sw] = *(const short8*)(bf + (size_t)(it + 2) * 1024);
            }
        }

        if (dofc) {
            const int tt = 96 - s;
#pragma unroll
            for (int btl = 0; btl < 2; ++btl) {
                f32x4 v = fca[btl] + fcb4;
                *(f32x4*)&out[(size_t)(g * 128 + w * 32 + btl * 16 + l15) * (TT * FF)
                              + tt * FF + (c & 7) * 16 + quad * 4] = v;
            }
        }

        epilogue(acc, s, hout);
    }

    // ---- final projection: h_96 (hfrag0) -> out[:, 0, :] (fcq==0 blocks) ----
    if (fcq == 0) {
        grp_wait(95);
        f32x4 fca[2] = {{0.f,0.f,0.f,0.f},{0.f,0.f,0.f,0.f}};
        short8 Wf[2]; short8 Hb[2][2];
#pragma unroll
        for (int p = 0; p < 2; ++p) {
            Wf[p] = *(const short8*)(bf + (size_t)p * 1024);
#pragma unroll
            for (int btl = 0; btl < 2; ++btl)
                Hb[p][btl] = *(const short8*)(aB0 + btl * 16384 + p * 1024);
        }
#pragma unroll
        for (int it = 0; it < 16; ++it) {
            const int sl = it & 1;
            fca[0] = __builtin_amdgcn_mfma_f32_16x16x32_bf16(Wf[sl], Hb[sl][0], fca[0], 0, 0, 0);
            fca[1] = __builtin_amdgcn_mfma_f32_16x16x32_bf16(Wf[sl], Hb[sl][1], fca[1], 0, 0, 0);
            if (it + 2 < 16) {
                Wf[sl] = *(const short8*)(bf + (size_t)(it + 2) * 1024);
#pragma unroll
                for (int btl = 0; btl < 2; ++btl)
                    Hb[sl][btl] = *(const short8*)(aB0 + btl * 16384 + (it + 2) * 1024);
            }
        }
#pragma unroll
        for (int btl = 0; btl < 2; ++btl) {
            f32x4 v = fca[btl] + fcb4;
            *(f32x4*)&out[(size_t)(g * 128 + w * 32 + btl * 16 + l15) * (TT * FF)
                          + (c & 7) * 16 + quad * 4] = v;
        }
    }
}

extern "C" void kernel_launch(void* const* d_in, const int* in_sizes, int n_in,
                              void* d_out, int out_size, void* d_ws, size_t ws_size,
                              hipStream_t stream) {
    const float* hidden = (const float*)d_in[0];
    const float* w_ih   = (const float*)d_in[1];
    const float* w_hh   = (const float*)d_in[2];
    const float* b_ih   = (const float*)d_in[3];
    const float* b_hh   = (const float*)d_in[4];
    const float* fc_w   = (const float*)d_in[5];
    const float* fc_b   = (const float*)d_in[6];
    float* out = (float*)d_out;

    char* ws = (char*)d_ws;
    size_t off = 0;
    auto alloc = [&](size_t bytes) -> void* {
        void* p = ws + off;
        off += (bytes + 255) & ~(size_t)255;
        return p;
    };
    char* Wg   = (char*)alloc((size_t)NGATE * HH * 2);
    char* W0g  = (char*)alloc((size_t)NGATE * HH * 2);
    char* Wfc  = (char*)alloc((size_t)FF * HH * 2);
    float* bias  = (float*)alloc(NGATE * 4);
    float* bias0 = (float*)alloc(NGATE * 4);
    char* hfrag0 = (char*)alloc((size_t)BB * HH * 2);
    char* hfrag1 = (char*)alloc((size_t)BB * HH * 2);
    int* cnt = (int*)alloc((size_t)GRP * NSTEP * CPB * 4);

    build_weights<<<NTOT, 256, 0, stream>>>(w_ih, w_hh, b_ih, b_hh, fc_w, fc_b,
                                            Wg, W0g, Wfc, bias, bias0);
    init_misc<<<(BB * HH / 8 + 255) / 256, 256, 0, stream>>>(hidden, hfrag0, cnt);
    gru_persist<<<512, 256, 0, stream>>>(Wg, W0g, Wfc, bias, bias0, fc_b, hidden,
                                         hfrag0, hfrag1, out, cnt);
}

// Round 10
// 843.838 us; speedup vs baseline: 1.6570x; 1.6570x over previous
//
#include <hip/hip_runtime.h>
#include <hip/hip_bf16.h>

#define HH 512
#define FF 128
#define BB 2048
#define TT 96
#define NSTEP 96
#define NGATE 2048
#define NTOT 2176
#define GRP 16          // row groups (128 rows each) — XCD-local under id%8 dispatch
#define CPB 32          // col-part blocks per group

typedef short short8 __attribute__((ext_vector_type(8)));
typedef float f32x4 __attribute__((ext_vector_type(4)));

__device__ __forceinline__ float sigmoidf_(float x) { return 1.f / (1.f + __expf(-x)); }
__device__ __forceinline__ float tanhf_(float x) {
    float e = __expf(-2.f * fabsf(x));
    float t = (1.f - e) / (1.f + e);
    return x < 0.f ? -t : t;
}

// byte offset of element (m, k) in fragment order: 16(m) x 32(k) tiles of 1 KB,
// lane = (m&15) + 16*((k>>3)&3) holds bytes [lane*16, lane*16+16).
__device__ __forceinline__ size_t frag_off(int m, int k, int K) {
    return (size_t)((m >> 4) * (K >> 5) + (k >> 5)) * 1024
         + (size_t)(((k >> 3) & 3) * 256 + (m & 15) * 16 + (k & 7) * 2);
}

__device__ __forceinline__ short bf16bits(float f) {
    __hip_bfloat16 b = __float2bfloat16(f);
    return *(short*)&b;
}

// Gate-row layout (gates as the MFMA M dim): gate-row n (0..2047):
//   j = (n>>4)*4 + ((n>>2)&3), gate = n&3  (0=r, 1=z, 2=i_n(comb), 3=h_n)
// -> C fragment puts all 4 gates of one j into one lane's 4 acc registers
// (quad = j-within-tile, reg = gate). n>=2048: fc_w row -> Wfc.
// (verified correct in rounds 5/7)
__global__ __launch_bounds__(256) void build_weights(
    const float* __restrict__ w_ih, const float* __restrict__ w_hh,
    const float* __restrict__ b_ih, const float* __restrict__ b_hh,
    const float* __restrict__ fc_w, const float* __restrict__ fc_b,
    char* __restrict__ Wg, char* __restrict__ W0g, char* __restrict__ Wfc,
    float* __restrict__ bias, float* __restrict__ bias0)
{
    const int n = blockIdx.x;
    const int tid = threadIdx.x;
    __shared__ float wih_s[FF];
    const bool is_out = (n >= NGATE);
    int gate = 3, gidx = 0, f = 0;
    if (is_out) {
        f = n - NGATE;
    } else {
        int j = (n >> 4) * 4 + ((n >> 2) & 3);
        gate = n & 3;
        gidx = (gate == 0) ? j : (gate == 1) ? (512 + j) : (1024 + j);
    }
    if (!is_out && gate != 3 && tid < FF) wih_s[tid] = w_ih[gidx * FF + tid];
    __syncthreads();

    for (int k = tid; k < HH; k += 256) {
        float w, w0;
        if (is_out) {
            w = fc_w[f * HH + k];
            w0 = 0.f;
        } else if (gate == 3) {
            w = w_hh[gidx * HH + k];
            w0 = w;
        } else {
            float comb = 0.f;
#pragma unroll 8
            for (int ff2 = 0; ff2 < FF; ++ff2) comb += wih_s[ff2] * fc_w[ff2 * HH + k];
            if (gate == 2) { w = comb; w0 = 0.f; }
            else { float whh = w_hh[gidx * HH + k]; w = whh + comb; w0 = whh; }
        }
        if (is_out) {
            *(short*)(Wfc + frag_off(f, k, HH)) = bf16bits(w);
        } else {
            *(short*)(Wg  + frag_off(n, k, HH)) = bf16bits(w);
            *(short*)(W0g + frag_off(n, k, HH)) = bf16bits(w0);
        }
    }
    if (tid == 0 && !is_out) {
        float b, b0;
        float cb = 0.f;
        if (gate != 3)
            for (int ff2 = 0; ff2 < FF; ++ff2) cb += fc_b[ff2] * w_ih[gidx * FF + ff2];
        if (gate <= 1)      { float s2 = b_ih[gidx] + b_hh[gidx]; b = s2 + cb; b0 = s2; }
        else if (gate == 2) { b = b_ih[gidx] + cb; b0 = b_ih[gidx]; }
        else                { b = b_hh[gidx]; b0 = b_hh[gidx]; }
        bias[n] = b; bias0[n] = b0;
    }
}

// hidden (fp32 row-major) -> h_0 bf16 in fragment order; zero sync flags.
__global__ __launch_bounds__(256) void init_misc(
    const float* __restrict__ hidden, char* __restrict__ hfrag, int* __restrict__ cnt)
{
    int i = blockIdx.x * 256 + threadIdx.x;  // 131072 granules of 8 k-elements
    int row = i >> 6, k0 = (i & 63) << 3;
    short8 v;
#pragma unroll
    for (int t = 0; t < 8; ++t) v[t] = bf16bits(hidden[(size_t)row * HH + k0 + t]);
    *(short8*)(hfrag + frag_off(row, k0, HH)) = v;
    if (i < GRP * NSTEP * CPB) cnt[i] = 0;
}

// Persistent GRU, operand-swapped, 1-tile register-resident weights.
// 512 blocks = 16 groups x 32 col-parts, 2 blocks/CU (LDS 68 KB). Map g=id&15:
// co-resident blocks (id, id+256) serve the SAME group -> shared Hb panel via L1
// (r7-proven; cross-group maps / phase seeding failed r2/r4/r8).
// MFMA: A = gate weights (M = gate-row), B = h (N = batch, global).
// LDS-redundancy fix, sized to FIT THE REGISTER BUDGET (r9's 2-tile variant
// needed ~290 VGPR -> compiler pinned 128 and spilled to scratch, FETCH 25->516
// MB): hold only M-tile 0 in registers (Wreg[16] = 64 VGPR, loaded once);
// stream tiles 1-3 from LDS (3 ds_read_b128/it instead of 4). Total pressure
// ~185 VGPR < 256 cap (launch_bounds(256,2)); 2x185 < 512/SIMD keeps 2
// waves/SIMD; occupancy stays LDS-bound at 2 blocks/CU. All Wreg indices are
// compile-time (full unroll). Depth-6 Hb window, lane-local shfl-free epilogue,
// fc deduped by step-phase (s&3 == c>>3) — all r7-proven.
__global__ __launch_bounds__(256, 2) void gru_persist(
    const char* __restrict__ Wg, const char* __restrict__ W0g, const char* __restrict__ Wfc,
    const float* __restrict__ bias, const float* __restrict__ bias0,
    const float* __restrict__ fc_b, const float* __restrict__ hidden,
    char* __restrict__ hfrag0, char* __restrict__ hfrag1,
    float* __restrict__ out, int* __restrict__ cnt)
{
    __shared__ __align__(16) short Bs[32768];   // 64 KB weights: [mt(4)][chunk(16)][lane*8]
    __shared__ __align__(16) short hfr[2048];   // 4 KB packed h_new [row(128)][col(16)]

    const int tid = threadIdx.x;
    const int lane = tid & 63, w = tid >> 6;
    const int l15 = lane & 15, quad = lane >> 4;
    const int g = blockIdx.x & 15, c = blockIdx.x >> 4;   // group on XCD (g&7)

    const char* aB0 = hfrag0 + (size_t)(g * 8 + w * 2) * 16384 + lane * 16;
    const char* aB1 = hfrag1 + (size_t)(g * 8 + w * 2) * 16384 + lane * 16;
    const char* bf  = Wfc + (size_t)(c & 7) * 16384 + lane * 16;
    const char* wlds = (const char*)Bs + lane * 16;
    const int fcq = c >> 3;                    // this block's fc step-phase

    f32x4 bv4[4];
#pragma unroll
    for (int mt = 0; mt < 4; ++mt)
        bv4[mt] = *(const f32x4*)&bias[c * 64 + mt * 16 + quad * 4];
    const f32x4 fcb4 = *(const f32x4*)&fc_b[(c & 7) * 16 + quad * 4];

    // fp32 carry h: carry[mt][btl] for (batch = g*128 + w*32 + btl*16 + l15,
    //                                   hcol = c*16 + mt*4 + quad)
    float carry[4][2];
#pragma unroll
    for (int mt = 0; mt < 4; ++mt)
#pragma unroll
        for (int btl = 0; btl < 2; ++btl)
            carry[mt][btl] =
                hidden[(size_t)(g * 128 + w * 32 + btl * 16 + l15) * HH
                       + c * 16 + mt * 4 + quad];

    int* const fl = cnt + g * (NSTEP * CPB);   // flags for this group: [s][c]

    // ---- stage this block's 64 gate rows of Wg into LDS (once) ----
    {
        const char* wsrc = Wg + (size_t)c * 65536;
#pragma unroll
        for (int i = 0; i < 16; ++i) {
            int idx = i * 256 + tid;
            *(int4*)((char*)Bs + idx * 16) = *(const int4*)(wsrc + (size_t)idx * 16);
        }
    }
    __syncthreads();

    // ---- M-tile 0 -> registers, once (64 VGPR; tiles 1-3 stay in LDS) ----
    short8 Wreg[16];
#pragma unroll
    for (int p = 0; p < 16; ++p)
        Wreg[p] = *(const short8*)(wlds + (size_t)p * 1024);

    // wait for the group's step-s broadcast (32 flags), then invalidate vector L1.
    auto grp_wait = [&](int s) {
        if (w == 0) {
            if (lane < 32) {
                const int* fp = fl + s * CPB + lane;
                while (__hip_atomic_load(fp, __ATOMIC_RELAXED, __HIP_MEMORY_SCOPE_AGENT) == 0)
                    __builtin_amdgcn_s_sleep(1);
            }
            asm volatile("buffer_inv sc0\n\ts_waitcnt vmcnt(0)" ::: "memory");
        }
        __syncthreads();
        asm volatile("" ::: "memory");
    };

    // lane-local full-wave gates -> carry -> hfr pack -> frag store -> signal
    auto epilogue = [&](f32x4 (&acc)[4][2], int s, char* hout) {
#pragma unroll
        for (int mt = 0; mt < 4; ++mt)
#pragma unroll
            for (int btl = 0; btl < 2; ++btl) {
                f32x4 a = acc[mt][btl];
                float r  = sigmoidf_(a[0]);
                float z  = sigmoidf_(a[1]);
                float nv = tanhf_(a[2] + r * a[3]);
                float hn = (1.f - z) * nv + z * carry[mt][btl];
                carry[mt][btl] = hn;
                hfr[(w * 32 + btl * 16 + l15) * 16 + mt * 4 + quad] = bf16bits(hn);
            }
        __syncthreads();
        {
            int lrow = tid >> 1, half = tid & 1;
            size_t off = (size_t)((g * 8 + (lrow >> 4)) * 16 + (c >> 1)) * 1024
                       + (size_t)((((c << 1) + half) & 3) * 256 + (lrow & 15) * 16);
            *(int4*)(hout + off) = *(const int4*)&hfr[lrow * 16 + half * 8];
        }
        asm volatile("s_waitcnt vmcnt(0)" ::: "memory");
        __syncthreads();
        if (tid == 0)
            __hip_atomic_store(fl + s * CPB + c, 1, __ATOMIC_RELAXED, __HIP_MEMORY_SCOPE_AGENT);
    };

    // ---- step 0: x=0 weights streamed from global (one step, amortized) ----
    {
        f32x4 acc[4][2];
#pragma unroll
        for (int mt = 0; mt < 4; ++mt) {
            f32x4 b0 = *(const f32x4*)&bias0[c * 64 + mt * 16 + quad * 4];
            acc[mt][0] = b0; acc[mt][1] = b0;
        }
        const char* w0b = W0g + (size_t)c * 65536 + lane * 16;
        short8 W0[2][4]; short8 Hb[2][2];
#pragma unroll
        for (int p = 0; p < 2; ++p) {
#pragma unroll
            for (int mt = 0; mt < 4; ++mt)
                W0[p][mt] = *(const short8*)(w0b + (size_t)(mt * 16 + p) * 1024);
#pragma unroll
            for (int btl = 0; btl < 2; ++btl)
                Hb[p][btl] = *(const short8*)(aB0 + btl * 16384 + p * 1024);
        }
#pragma unroll
        for (int it = 0; it < 16; ++it) {
            const int sl = it & 1;
#pragma unroll
            for (int mt = 0; mt < 4; ++mt)
#pragma unroll
                for (int btl = 0; btl < 2; ++btl)
                    acc[mt][btl] = __builtin_amdgcn_mfma_f32_16x16x32_bf16(W0[sl][mt], Hb[sl][btl], acc[mt][btl], 0, 0, 0);
            if (it + 2 < 16) {
#pragma unroll
                for (int mt = 0; mt < 4; ++mt)
                    W0[sl][mt] = *(const short8*)(w0b + (size_t)(mt * 16 + it + 2) * 1024);
#pragma unroll
                for (int btl = 0; btl < 2; ++btl)
                    Hb[sl][btl] = *(const short8*)(aB0 + btl * 16384 + (it + 2) * 1024);
            }
        }
        epilogue(acc, 0, hfrag1);
    }

    // ---- steps 1..95: mt 0 from Wreg, mt 1-3 from LDS, Hb depth-6, fc /4 ----
    for (int s = 1; s < 96; ++s) {
        const char* ab = (s & 1) ? aB1 : aB0;
        char* hout = (s & 1) ? hfrag0 : hfrag1;
        const bool dofc = ((s & 3) == fcq);

        f32x4 acc[4][2];
#pragma unroll
        for (int mt = 0; mt < 4; ++mt) {
            acc[mt][0] = bv4[mt]; acc[mt][1] = bv4[mt];
        }
        f32x4 fca[2] = {{0.f,0.f,0.f,0.f},{0.f,0.f,0.f,0.f}};

        // barrier-independent preloads: LDS weight frags mt 1-3 (+ fc frags)
        short8 Wa[2][3]; short8 Wf[2];
#pragma unroll
        for (int p = 0; p < 2; ++p)
#pragma unroll
            for (int m2 = 0; m2 < 3; ++m2)
                Wa[p][m2] = *(const short8*)(wlds + (size_t)((1 + m2) * 16 + p) * 1024);
        if (dofc) {
            Wf[0] = *(const short8*)(bf);
            Wf[1] = *(const short8*)(bf + 1024);
        }

        grp_wait(s - 1);

        short8 Hb[6][2];
#pragma unroll
        for (int p = 0; p < 6; ++p)
#pragma unroll
            for (int btl = 0; btl < 2; ++btl)
                Hb[p][btl] = *(const short8*)(ab + btl * 16384 + p * 1024);

#pragma unroll
        for (int it = 0; it < 16; ++it) {
            const int sa = it % 6, sw = it & 1;
#pragma unroll
            for (int btl = 0; btl < 2; ++btl) {
                acc[0][btl] = __builtin_amdgcn_mfma_f32_16x16x32_bf16(Wreg[it],  Hb[sa][btl], acc[0][btl], 0, 0, 0);
                acc[1][btl] = __builtin_amdgcn_mfma_f32_16x16x32_bf16(Wa[sw][0], Hb[sa][btl], acc[1][btl], 0, 0, 0);
                acc[2][btl] = __builtin_amdgcn_mfma_f32_16x16x32_bf16(Wa[sw][1], Hb[sa][btl], acc[2][btl], 0, 0, 0);
                acc[3][btl] = __builtin_amdgcn_mfma_f32_16x16x32_bf16(Wa[sw][2], Hb[sa][btl], acc[3][btl], 0, 0, 0);
            }
            if (dofc) {
                fca[0] = __builtin_amdgcn_mfma_f32_16x16x32_bf16(Wf[sw], Hb[sa][0], fca[0], 0, 0, 0);
                fca[1] = __builtin_amdgcn_mfma_f32_16x16x32_bf16(Wf[sw], Hb[sa][1], fca[1], 0, 0, 0);
            }
            if (it + 6 < 16) {
#pragma unroll
                for (int btl = 0; btl < 2; ++btl)
                    Hb[sa][btl] = *(const short8*)(ab + btl * 16384 + (it + 6) * 1024);
            }
            if (it + 2 < 16) {
#pragma unroll
                for (int m2 = 0; m2 < 3; ++m2)
                    Wa[sw][m2] = *(const short8*)(wlds + (size_t)((1 + m2) * 16 + it + 2) * 1024);
                if (dofc) Wf[sw] = *(const short8*)(bf + (size_t)(it + 2) * 1024);
            }
        }

        if (dofc) {
            const int tt = 96 - s;
#pragma unroll
            for (int btl = 0; btl < 2; ++btl) {
                f32x4 v = fca[btl] + fcb4;
                *(f32x4*)&out[(size_t)(g * 128 + w * 32 + btl * 16 + l15) * (TT * FF)
                              + tt * FF + (c & 7) * 16 + quad * 4] = v;
            }
        }

        epilogue(acc, s, hout);
    }

    // ---- final projection: h_96 (hfrag0) -> out[:, 0, :] (fcq==0 blocks) ----
    if (fcq == 0) {
        grp_wait(95);
        f32x4 fca[2] = {{0.f,0.f,0.f,0.f},{0.f,0.f,0.f,0.f}};
        short8 Wf[2]; short8 Hb[2][2];
#pragma unroll
        for (int p = 0; p < 2; ++p) {
            Wf[p] = *(const short8*)(bf + (size_t)p * 1024);
#pragma unroll
            for (int btl = 0; btl < 2; ++btl)
                Hb[p][btl] = *(const short8*)(aB0 + btl * 16384 + p * 1024);
        }
#pragma unroll
        for (int it = 0; it < 16; ++it) {
            const int sl = it & 1;
            fca[0] = __builtin_amdgcn_mfma_f32_16x16x32_bf16(Wf[sl], Hb[sl][0], fca[0], 0, 0, 0);
            fca[1] = __builtin_amdgcn_mfma_f32_16x16x32_bf16(Wf[sl], Hb[sl][1], fca[1], 0, 0, 0);
            if (it + 2 < 16) {
                Wf[sl] = *(const short8*)(bf + (size_t)(it + 2) * 1024);
#pragma unroll
                for (int btl = 0; btl < 2; ++btl)
                    Hb[sl][btl] = *(const short8*)(aB0 + btl * 16384 + (it + 2) * 1024);
            }
        }
#pragma unroll
        for (int btl = 0; btl < 2; ++btl) {
            f32x4 v = fca[btl] + fcb4;
            *(f32x4*)&out[(size_t)(g * 128 + w * 32 + btl * 16 + l15) * (TT * FF)
                          + (c & 7) * 16 + quad * 4] = v;
        }
    }
}

extern "C" void kernel_launch(void* const* d_in, const int* in_sizes, int n_in,
                              void* d_out, int out_size, void* d_ws, size_t ws_size,
                              hipStream_t stream) {
    const float* hidden = (const float*)d_in[0];
    const float* w_ih   = (const float*)d_in[1];
    const float* w_hh   = (const float*)d_in[2];
    const float* b_ih   = (const float*)d_in[3];
    const float* b_hh   = (const float*)d_in[4];
    const float* fc_w   = (const float*)d_in[5];
    const float* fc_b   = (const float*)d_in[6];
    float* out = (float*)d_out;

    char* ws = (char*)d_ws;
    size_t off = 0;
    auto alloc = [&](size_t bytes) -> void* {
        void* p = ws + off;
        off += (bytes + 255) & ~(size_t)255;
        return p;
    };
    char* Wg   = (char*)alloc((size_t)NGATE * HH * 2);
    char* W0g  = (char*)alloc((size_t)NGATE * HH * 2);
    char* Wfc  = (char*)alloc((size_t)FF * HH * 2);
    float* bias  = (float*)alloc(NGATE * 4);
    float* bias0 = (float*)alloc(NGATE * 4);
    char* hfrag0 = (char*)alloc((size_t)BB * HH * 2);
    char* hfrag1 = (char*)alloc((size_t)BB * HH * 2);
    int* cnt = (int*)alloc((size_t)GRP * NSTEP * CPB * 4);

    build_weights<<<NTOT, 256, 0, stream>>>(w_ih, w_hh, b_ih, b_hh, fc_w, fc_b,
                                            Wg, W0g, Wfc, bias, bias0);
    init_misc<<<(BB * HH / 8 + 255) / 256, 256, 0, stream>>>(hidden, hfrag0, cnt);
    gru_persist<<<512, 256, 0, stream>>>(Wg, W0g, Wfc, bias, bias0, fc_b, hidden,
                                         hfrag0, hfrag1, out, cnt);
}

// Round 11
// 805.707 us; speedup vs baseline: 1.7354x; 1.0473x over previous
//
#include <hip/hip_runtime.h>
#include <hip/hip_bf16.h>

#define HH 512
#define FF 128
#define BB 2048
#define TT 96
#define NSTEP 96
#define NGATE 2048
#define NTOT 2176
#define GRP 16          // row groups (128 rows each) — XCD-local under id%8 dispatch
#define CPB 32          // col-part blocks per group

typedef short short8 __attribute__((ext_vector_type(8)));
typedef float f32x4 __attribute__((ext_vector_type(4)));

__device__ __forceinline__ float sigmoidf_(float x) { return 1.f / (1.f + __expf(-x)); }
__device__ __forceinline__ float tanhf_(float x) {
    float e = __expf(-2.f * fabsf(x));
    float t = (1.f - e) / (1.f + e);
    return x < 0.f ? -t : t;
}

// byte offset of element (m, k) in fragment order: 16(m) x 32(k) tiles of 1 KB,
// lane = (m&15) + 16*((k>>3)&3) holds bytes [lane*16, lane*16+16).
__device__ __forceinline__ size_t frag_off(int m, int k, int K) {
    return (size_t)((m >> 4) * (K >> 5) + (k >> 5)) * 1024
         + (size_t)(((k >> 3) & 3) * 256 + (m & 15) * 16 + (k & 7) * 2);
}

__device__ __forceinline__ short bf16bits(float f) {
    __hip_bfloat16 b = __float2bfloat16(f);
    return *(short*)&b;
}

// Gate-row layout (gates as the MFMA M dim): gate-row n (0..2047):
//   j = (n>>4)*4 + ((n>>2)&3), gate = n&3  (0=r, 1=z, 2=i_n(comb), 3=h_n)
// -> C fragment puts all 4 gates of one j into one lane's 4 acc registers
// (quad = j-within-tile, reg = gate). n>=2048: fc_w row -> Wfc.
// (verified correct in rounds 5/7)
__global__ __launch_bounds__(256) void build_weights(
    const float* __restrict__ w_ih, const float* __restrict__ w_hh,
    const float* __restrict__ b_ih, const float* __restrict__ b_hh,
    const float* __restrict__ fc_w, const float* __restrict__ fc_b,
    char* __restrict__ Wg, char* __restrict__ W0g, char* __restrict__ Wfc,
    float* __restrict__ bias, float* __restrict__ bias0)
{
    const int n = blockIdx.x;
    const int tid = threadIdx.x;
    __shared__ float wih_s[FF];
    const bool is_out = (n >= NGATE);
    int gate = 3, gidx = 0, f = 0;
    if (is_out) {
        f = n - NGATE;
    } else {
        int j = (n >> 4) * 4 + ((n >> 2) & 3);
        gate = n & 3;
        gidx = (gate == 0) ? j : (gate == 1) ? (512 + j) : (1024 + j);
    }
    if (!is_out && gate != 3 && tid < FF) wih_s[tid] = w_ih[gidx * FF + tid];
    __syncthreads();

    for (int k = tid; k < HH; k += 256) {
        float w, w0;
        if (is_out) {
            w = fc_w[f * HH + k];
            w0 = 0.f;
        } else if (gate == 3) {
            w = w_hh[gidx * HH + k];
            w0 = w;
        } else {
            float comb = 0.f;
#pragma unroll 8
            for (int ff2 = 0; ff2 < FF; ++ff2) comb += wih_s[ff2] * fc_w[ff2 * HH + k];
            if (gate == 2) { w = comb; w0 = 0.f; }
            else { float whh = w_hh[gidx * HH + k]; w = whh + comb; w0 = whh; }
        }
        if (is_out) {
            *(short*)(Wfc + frag_off(f, k, HH)) = bf16bits(w);
        } else {
            *(short*)(Wg  + frag_off(n, k, HH)) = bf16bits(w);
            *(short*)(W0g + frag_off(n, k, HH)) = bf16bits(w0);
        }
    }
    if (tid == 0 && !is_out) {
        float b, b0;
        float cb = 0.f;
        if (gate != 3)
            for (int ff2 = 0; ff2 < FF; ++ff2) cb += fc_b[ff2] * w_ih[gidx * FF + ff2];
        if (gate <= 1)      { float s2 = b_ih[gidx] + b_hh[gidx]; b = s2 + cb; b0 = s2; }
        else if (gate == 2) { b = b_ih[gidx] + cb; b0 = b_ih[gidx]; }
        else                { b = b_hh[gidx]; b0 = b_hh[gidx]; }
        bias[n] = b; bias0[n] = b0;
    }
}

// hidden (fp32 row-major) -> h_0 bf16 in fragment order; zero sync flags.
__global__ __launch_bounds__(256) void init_misc(
    const float* __restrict__ hidden, char* __restrict__ hfrag, int* __restrict__ cnt)
{
    int i = blockIdx.x * 256 + threadIdx.x;  // 131072 granules of 8 k-elements
    int row = i >> 6, k0 = (i & 63) << 3;
    short8 v;
#pragma unroll
    for (int t = 0; t < 8; ++t) v[t] = bf16bits(hidden[(size_t)row * HH + k0 + t]);
    *(short8*)(hfrag + frag_off(row, k0, HH)) = v;
    if (i < GRP * NSTEP * CPB) cnt[i] = 0;
}

// Persistent GRU, operand-swapped, 1-tile register-resident weights (fixed).
// r10's variant spilled: the allocator pinned 128 VGPR (targeting 4 waves/EU
// occupancy that the 68 KB LDS makes unreachable) and pushed Wreg[16] to
// scratch (WRITE 122->172 MB at VGPR_Count 128). Two deterministic fixes:
//  1. amdgpu_waves_per_eu(2,2): min=max=2 waves/EU -> VGPR budget exactly 256,
//     no incentive to spill below it (occupancy is LDS-bound at 2 blocks/CU).
//  2. Wr0..Wr15 as NAMED variables + macro-unrolled K-loop: the weight tile
//     can never be runtime-indexed -> structurally cannot go to scratch.
// Everything else r7-proven: map g=id&15 (co-resident blocks share the Hb
// panel via L1), plain cached h loads + buffer_inv after flag detect,
// vmcnt(0)+sync before signal, depth-6 Hb window, lane-local shfl-free
// epilogue, fc deduped by step-phase (s&3 == c>>3).
__attribute__((amdgpu_waves_per_eu(2, 2)))
__global__ __launch_bounds__(256) void gru_persist(
    const char* __restrict__ Wg, const char* __restrict__ W0g, const char* __restrict__ Wfc,
    const float* __restrict__ bias, const float* __restrict__ bias0,
    const float* __restrict__ fc_b, const float* __restrict__ hidden,
    char* __restrict__ hfrag0, char* __restrict__ hfrag1,
    float* __restrict__ out, int* __restrict__ cnt)
{
    __shared__ __align__(16) short Bs[32768];   // 64 KB weights: [mt(4)][chunk(16)][lane*8]
    __shared__ __align__(16) short hfr[2048];   // 4 KB packed h_new [row(128)][col(16)]

    const int tid = threadIdx.x;
    const int lane = tid & 63, w = tid >> 6;
    const int l15 = lane & 15, quad = lane >> 4;
    const int g = blockIdx.x & 15, c = blockIdx.x >> 4;   // group on XCD (g&7)

    const char* aB0 = hfrag0 + (size_t)(g * 8 + w * 2) * 16384 + lane * 16;
    const char* aB1 = hfrag1 + (size_t)(g * 8 + w * 2) * 16384 + lane * 16;
    const char* bf  = Wfc + (size_t)(c & 7) * 16384 + lane * 16;
    const char* wlds = (const char*)Bs + lane * 16;
    const int fcq = c >> 3;                    // this block's fc step-phase

    f32x4 bv4[4];
#pragma unroll
    for (int mt = 0; mt < 4; ++mt)
        bv4[mt] = *(const f32x4*)&bias[c * 64 + mt * 16 + quad * 4];
    const f32x4 fcb4 = *(const f32x4*)&fc_b[(c & 7) * 16 + quad * 4];

    // fp32 carry h: carry[mt][btl] for (batch = g*128 + w*32 + btl*16 + l15,
    //                                   hcol = c*16 + mt*4 + quad)
    float carry[4][2];
#pragma unroll
    for (int mt = 0; mt < 4; ++mt)
#pragma unroll
        for (int btl = 0; btl < 2; ++btl)
            carry[mt][btl] =
                hidden[(size_t)(g * 128 + w * 32 + btl * 16 + l15) * HH
                       + c * 16 + mt * 4 + quad];

    int* const fl = cnt + g * (NSTEP * CPB);   // flags for this group: [s][c]

    // ---- stage this block's 64 gate rows of Wg into LDS (once) ----
    {
        const char* wsrc = Wg + (size_t)c * 65536;
#pragma unroll
        for (int i = 0; i < 16; ++i) {
            int idx = i * 256 + tid;
            *(int4*)((char*)Bs + idx * 16) = *(const int4*)(wsrc + (size_t)idx * 16);
        }
    }
    __syncthreads();

    // ---- M-tile 0 -> NAMED registers, once (64 VGPR; tiles 1-3 stay in LDS) ----
    short8 Wr0, Wr1, Wr2, Wr3, Wr4, Wr5, Wr6, Wr7,
           Wr8, Wr9, Wr10, Wr11, Wr12, Wr13, Wr14, Wr15;
#define LOADW(P) Wr##P = *(const short8*)(wlds + (size_t)(P) * 1024);
    LOADW(0) LOADW(1) LOADW(2) LOADW(3) LOADW(4) LOADW(5) LOADW(6) LOADW(7)
    LOADW(8) LOADW(9) LOADW(10) LOADW(11) LOADW(12) LOADW(13) LOADW(14) LOADW(15)
#undef LOADW

    // wait for the group's step-s broadcast (32 flags), then invalidate vector L1.
    auto grp_wait = [&](int s) {
        if (w == 0) {
            if (lane < 32) {
                const int* fp = fl + s * CPB + lane;
                while (__hip_atomic_load(fp, __ATOMIC_RELAXED, __HIP_MEMORY_SCOPE_AGENT) == 0)
                    __builtin_amdgcn_s_sleep(1);
            }
            asm volatile("buffer_inv sc0\n\ts_waitcnt vmcnt(0)" ::: "memory");
        }
        __syncthreads();
        asm volatile("" ::: "memory");
    };

    // lane-local full-wave gates -> carry -> hfr pack -> frag store -> signal
    auto epilogue = [&](f32x4 (&acc)[4][2], int s, char* hout) {
#pragma unroll
        for (int mt = 0; mt < 4; ++mt)
#pragma unroll
            for (int btl = 0; btl < 2; ++btl) {
                f32x4 a = acc[mt][btl];
                float r  = sigmoidf_(a[0]);
                float z  = sigmoidf_(a[1]);
                float nv = tanhf_(a[2] + r * a[3]);
                float hn = (1.f - z) * nv + z * carry[mt][btl];
                carry[mt][btl] = hn;
                hfr[(w * 32 + btl * 16 + l15) * 16 + mt * 4 + quad] = bf16bits(hn);
            }
        __syncthreads();
        {
            int lrow = tid >> 1, half = tid & 1;
            size_t off = (size_t)((g * 8 + (lrow >> 4)) * 16 + (c >> 1)) * 1024
                       + (size_t)((((c << 1) + half) & 3) * 256 + (lrow & 15) * 16);
            *(int4*)(hout + off) = *(const int4*)&hfr[lrow * 16 + half * 8];
        }
        asm volatile("s_waitcnt vmcnt(0)" ::: "memory");
        __syncthreads();
        if (tid == 0)
            __hip_atomic_store(fl + s * CPB + c, 1, __ATOMIC_RELAXED, __HIP_MEMORY_SCOPE_AGENT);
    };

    // ---- step 0: x=0 weights streamed from global (one step, amortized) ----
    {
        f32x4 acc[4][2];
#pragma unroll
        for (int mt = 0; mt < 4; ++mt) {
            f32x4 b0 = *(const f32x4*)&bias0[c * 64 + mt * 16 + quad * 4];
            acc[mt][0] = b0; acc[mt][1] = b0;
        }
        const char* w0b = W0g + (size_t)c * 65536 + lane * 16;
        short8 W0[2][4]; short8 Hb[2][2];
#pragma unroll
        for (int p = 0; p < 2; ++p) {
#pragma unroll
            for (int mt = 0; mt < 4; ++mt)
                W0[p][mt] = *(const short8*)(w0b + (size_t)(mt * 16 + p) * 1024);
#pragma unroll
            for (int btl = 0; btl < 2; ++btl)
                Hb[p][btl] = *(const short8*)(aB0 + btl * 16384 + p * 1024);
        }
#pragma unroll
        for (int it = 0; it < 16; ++it) {
            const int sl = it & 1;
#pragma unroll
            for (int mt = 0; mt < 4; ++mt)
#pragma unroll
                for (int btl = 0; btl < 2; ++btl)
                    acc[mt][btl] = __builtin_amdgcn_mfma_f32_16x16x32_bf16(W0[sl][mt], Hb[sl][btl], acc[mt][btl], 0, 0, 0);
            if (it + 2 < 16) {
#pragma unroll
                for (int mt = 0; mt < 4; ++mt)
                    W0[sl][mt] = *(const short8*)(w0b + (size_t)(mt * 16 + it + 2) * 1024);
#pragma unroll
                for (int btl = 0; btl < 2; ++btl)
                    Hb[sl][btl] = *(const short8*)(aB0 + btl * 16384 + (it + 2) * 1024);
            }
        }
        epilogue(acc, 0, hfrag1);
    }

    // ---- steps 1..95: mt 0 from Wr*, mt 1-3 from LDS, Hb depth-6, fc /4 ----
    for (int s = 1; s < 96; ++s) {
        const char* ab = (s & 1) ? aB1 : aB0;
        char* hout = (s & 1) ? hfrag0 : hfrag1;
        const bool dofc = ((s & 3) == fcq);

        f32x4 acc[4][2];
#pragma unroll
        for (int mt = 0; mt < 4; ++mt) {
            acc[mt][0] = bv4[mt]; acc[mt][1] = bv4[mt];
        }
        f32x4 fca[2] = {{0.f,0.f,0.f,0.f},{0.f,0.f,0.f,0.f}};

        // barrier-independent preloads: LDS weight frags mt 1-3 (+ fc frags)
        short8 Wa[2][3]; short8 Wf[2];
#pragma unroll
        for (int p = 0; p < 2; ++p)
#pragma unroll
            for (int m2 = 0; m2 < 3; ++m2)
                Wa[p][m2] = *(const short8*)(wlds + (size_t)((1 + m2) * 16 + p) * 1024);
        if (dofc) {
            Wf[0] = *(const short8*)(bf);
            Wf[1] = *(const short8*)(bf + 1024);
        }

        grp_wait(s - 1);

        short8 Hb[6][2];
#pragma unroll
        for (int p = 0; p < 6; ++p)
#pragma unroll
            for (int btl = 0; btl < 2; ++btl)
                Hb[p][btl] = *(const short8*)(ab + btl * 16384 + p * 1024);

        // macro-unrolled K-loop: all indices literal -> nothing runtime-indexed
#define KSTEP(IT, WR) { \
        constexpr int sa = (IT) % 6, sw = (IT) & 1; \
        acc[0][0] = __builtin_amdgcn_mfma_f32_16x16x32_bf16(WR,        Hb[sa][0], acc[0][0], 0, 0, 0); \
        acc[1][0] = __builtin_amdgcn_mfma_f32_16x16x32_bf16(Wa[sw][0], Hb[sa][0], acc[1][0], 0, 0, 0); \
        acc[2][0] = __builtin_amdgcn_mfma_f32_16x16x32_bf16(Wa[sw][1], Hb[sa][0], acc[2][0], 0, 0, 0); \
        acc[3][0] = __builtin_amdgcn_mfma_f32_16x16x32_bf16(Wa[sw][2], Hb[sa][0], acc[3][0], 0, 0, 0); \
        acc[0][1] = __builtin_amdgcn_mfma_f32_16x16x32_bf16(WR,        Hb[sa][1], acc[0][1], 0, 0, 0); \
        acc[1][1] = __builtin_amdgcn_mfma_f32_16x16x32_bf16(Wa[sw][0], Hb[sa][1], acc[1][1], 0, 0, 0); \
        acc[2][1] = __builtin_amdgcn_mfma_f32_16x16x32_bf16(Wa[sw][1], Hb[sa][1], acc[2][1], 0, 0, 0); \
        acc[3][1] = __builtin_amdgcn_mfma_f32_16x16x32_bf16(Wa[sw][2], Hb[sa][1], acc[3][1], 0, 0, 0); \
        if (dofc) { \
            fca[0] = __builtin_amdgcn_mfma_f32_16x16x32_bf16(Wf[sw], Hb[sa][0], fca[0], 0, 0, 0); \
            fca[1] = __builtin_amdgcn_mfma_f32_16x16x32_bf16(Wf[sw], Hb[sa][1], fca[1], 0, 0, 0); \
        } \
        if ((IT) + 6 < 16) { \
            Hb[sa][0] = *(const short8*)(ab + 0 * 16384 + ((IT) + 6) * 1024); \
            Hb[sa][1] = *(const short8*)(ab + 1 * 16384 + ((IT) + 6) * 1024); \
        } \
        if ((IT) + 2 < 16) { \
            Wa[sw][0] = *(const short8*)(wlds + (size_t)(1 * 16 + (IT) + 2) * 1024); \
            Wa[sw][1] = *(const short8*)(wlds + (size_t)(2 * 16 + (IT) + 2) * 1024); \
            Wa[sw][2] = *(const short8*)(wlds + (size_t)(3 * 16 + (IT) + 2) * 1024); \
            if (dofc) Wf[sw] = *(const short8*)(bf + (size_t)((IT) + 2) * 1024); \
        } \
    }
        KSTEP(0, Wr0)  KSTEP(1, Wr1)  KSTEP(2, Wr2)  KSTEP(3, Wr3)
        KSTEP(4, Wr4)  KSTEP(5, Wr5)  KSTEP(6, Wr6)  KSTEP(7, Wr7)
        KSTEP(8, Wr8)  KSTEP(9, Wr9)  KSTEP(10, Wr10) KSTEP(11, Wr11)
        KSTEP(12, Wr12) KSTEP(13, Wr13) KSTEP(14, Wr14) KSTEP(15, Wr15)
#undef KSTEP

        if (dofc) {
            const int tt = 96 - s;
#pragma unroll
            for (int btl = 0; btl < 2; ++btl) {
                f32x4 v = fca[btl] + fcb4;
                *(f32x4*)&out[(size_t)(g * 128 + w * 32 + btl * 16 + l15) * (TT * FF)
                              + tt * FF + (c & 7) * 16 + quad * 4] = v;
            }
        }

        epilogue(acc, s, hout);
    }

    // ---- final projection: h_96 (hfrag0) -> out[:, 0, :] (fcq==0 blocks) ----
    if (fcq == 0) {
        grp_wait(95);
        f32x4 fca[2] = {{0.f,0.f,0.f,0.f},{0.f,0.f,0.f,0.f}};
        short8 Wf[2]; short8 Hb[2][2];
#pragma unroll
        for (int p = 0; p < 2; ++p) {
            Wf[p] = *(const short8*)(bf + (size_t)p * 1024);
#pragma unroll
            for (int btl = 0; btl < 2; ++btl)
                Hb[p][btl] = *(const short8*)(aB0 + btl * 16384 + p * 1024);
        }
#pragma unroll
        for (int it = 0; it < 16; ++it) {
            const int sl = it & 1;
            fca[0] = __builtin_amdgcn_mfma_f32_16x16x32_bf16(Wf[sl], Hb[sl][0], fca[0], 0, 0, 0);
            fca[1] = __builtin_amdgcn_mfma_f32_16x16x32_bf16(Wf[sl], Hb[sl][1], fca[1], 0, 0, 0);
            if (it + 2 < 16) {
                Wf[sl] = *(const short8*)(bf + (size_t)(it + 2) * 1024);
#pragma unroll
                for (int btl = 0; btl < 2; ++btl)
                    Hb[sl][btl] = *(const short8*)(aB0 + btl * 16384 + (it + 2) * 1024);
            }
        }
#pragma unroll
        for (int btl = 0; btl < 2; ++btl) {
            f32x4 v = fca[btl] + fcb4;
            *(f32x4*)&out[(size_t)(g * 128 + w * 32 + btl * 16 + l15) * (TT * FF)
                          + (c & 7) * 16 + quad * 4] = v;
        }
    }
}

extern "C" void kernel_launch(void* const* d_in, const int* in_sizes, int n_in,
                              void* d_out, int out_size, void* d_ws, size_t ws_size,
                              hipStream_t stream) {
    const float* hidden = (const float*)d_in[0];
    const float* w_ih   = (const float*)d_in[1];
    const float* w_hh   = (const float*)d_in[2];
    const float* b_ih   = (const float*)d_in[3];
    const float* b_hh   = (const float*)d_in[4];
    const float* fc_w   = (const float*)d_in[5];
    const float* fc_b   = (const float*)d_in[6];
    float* out = (float*)d_out;

    char* ws = (char*)d_ws;
    size_t off = 0;
    auto alloc = [&](size_t bytes) -> void* {
        void* p = ws + off;
        off += (bytes + 255) & ~(size_t)255;
        return p;
    };
    char* Wg   = (char*)alloc((size_t)NGATE * HH * 2);
    char* W0g  = (char*)alloc((size_t)NGATE * HH * 2);
    char* Wfc  = (char*)alloc((size_t)FF * HH * 2);
    float* bias  = (float*)alloc(NGATE * 4);
    float* bias0 = (float*)alloc(NGATE * 4);
    char* hfrag0 = (char*)alloc((size_t)BB * HH * 2);
    char* hfrag1 = (char*)alloc((size_t)BB * HH * 2);
    int* cnt = (int*)alloc((size_t)GRP * NSTEP * CPB * 4);

    build_weights<<<NTOT, 256, 0, stream>>>(w_ih, w_hh, b_ih, b_hh, fc_w, fc_b,
                                            Wg, W0g, Wfc, bias, bias0);
    init_misc<<<(BB * HH / 8 + 255) / 256, 256, 0, stream>>>(hidden, hfrag0, cnt);
    gru_persist<<<512, 256, 0, stream>>>(Wg, W0g, Wfc, bias, bias0, fc_b, hidden,
                                         hfrag0, hfrag1, out, cnt);
}